// Round 1
// baseline (12263.443 us; speedup 1.0000x reference)
//
#include <hip/hip_runtime.h>

#define NN 8192
#define NE 131072
#define KNN 20
#define CH 512   // gram chunk rows

// ---------------- utility ----------------
__global__ void k_zero(float* p, int n){
  int i = blockIdx.x*256 + threadIdx.x;
  if (i < n) p[i] = 0.f;
}
__global__ void k_zero_i(int* p, int n){
  int i = blockIdx.x*256 + threadIdx.x;
  if (i < n) p[i] = 0;
}

// ---------------- graph prep ----------------
__global__ void k_count(const int* __restrict__ src, const int* __restrict__ dst,
                        int* cs, int* cd){
  int e = blockIdx.x*256 + threadIdx.x;
  if (e < NE){ atomicAdd(&cs[src[e]], 1); atomicAdd(&cd[dst[e]], 1); }
}
__global__ void k_deg(const int* cs, const int* cd, float* dout, float* din){
  int i = blockIdx.x*256 + threadIdx.x;
  if (i < NN){
    dout[i] = rsqrtf((float)max(cs[i], 1));
    din[i]  = rsqrtf((float)max(cd[i], 1));
  }
}
// single-block exclusive scan of cnt_dst -> row_off (N+1)
__global__ void k_scan(const int* __restrict__ cnt, int* __restrict__ off){
  __shared__ int sh[256];
  __shared__ int carry;
  int tid = threadIdx.x;
  if (tid == 0) carry = 0;
  __syncthreads();
  for (int base = 0; base < NN; base += 256){
    int v = cnt[base + tid];
    int x = v;
    sh[tid] = x; __syncthreads();
    for (int o = 1; o < 256; o <<= 1){
      int y = (tid >= o) ? sh[tid - o] : 0;
      __syncthreads();
      x += y; sh[tid] = x;
      __syncthreads();
    }
    off[base + tid] = carry + x - v;
    __syncthreads();
    if (tid == 255){
      carry += x;
      if (base + 256 == NN) off[NN] = carry;
    }
    __syncthreads();
  }
}
__global__ void k_fill(const int* __restrict__ src, const int* __restrict__ dst,
                       const int* __restrict__ roff, int* cursor, int* csr){
  int e = blockIdx.x*256 + threadIdx.x;
  if (e < NE){
    int d = dst[e];
    int p = atomicAdd(&cursor[d], 1);
    csr[roff[d] + p] = src[e];
  }
}

// ---------------- gconv1 fused (3 -> 256) ----------------
__global__ void k_gconv1(const float* __restrict__ feat, const int* __restrict__ roff,
                         const int* __restrict__ csr, const float* __restrict__ dout,
                         const float* __restrict__ din, const float* __restrict__ Wc1,
                         const float* __restrict__ bc1, float* __restrict__ h1){
  int wid = threadIdx.x >> 6, lane = threadIdx.x & 63;
  int i = blockIdx.x*4 + wid;
  float a0=0.f, a1=0.f, a2=0.f;
  int beg = roff[i], end = roff[i+1];
  for (int t = beg + lane; t < end; t += 64){
    int s = csr[t]; float w = dout[s];
    a0 += feat[s*3+0]*w; a1 += feat[s*3+1]*w; a2 += feat[s*3+2]*w;
  }
  for (int m = 32; m; m >>= 1){
    a0 += __shfl_xor(a0, m); a1 += __shfl_xor(a1, m); a2 += __shfl_xor(a2, m);
  }
  float dn = din[i];
  a0 *= dn; a1 *= dn; a2 *= dn;
  for (int c = lane; c < 256; c += 64){
    float r = a0*Wc1[c] + a1*Wc1[256+c] + a2*Wc1[512+c] + bc1[c];
    h1[(size_t)i*256 + c] = fmaxf(r, 0.f);
  }
}

// ---------------- row squared norms (C=256) ----------------
__global__ void k_sq(const float* __restrict__ X, float* __restrict__ sq){
  int wid = threadIdx.x >> 6, lane = threadIdx.x & 63;
  int i = blockIdx.x*4 + wid;
  float4 v = *(const float4*)&X[(size_t)i*256 + lane*4];
  float s = v.x*v.x + v.y*v.y + v.z*v.z + v.w*v.w;
  for (int m = 32; m; m >>= 1) s += __shfl_xor(s, m);
  if (lane == 0) sq[i] = s;
}

// ---------------- Gram chunk: G = Ar @ B^T, Ar CHx256, B 8192x256 ----------------
__global__ __launch_bounds__(256)
void k_gramNT(const float* __restrict__ Ar, const float* __restrict__ B,
              float* __restrict__ G){
  __shared__ float la[16][68], lb[16][68];
  int tid = threadIdx.x;
  int rb = blockIdx.y*64, cb = blockIdx.x*64;
  int lr = tid >> 2, lq = (tid & 3)*4;
  int ty = tid >> 4, tx = tid & 15;
  float acc[4][4] = {};
  for (int k0 = 0; k0 < 256; k0 += 16){
    __syncthreads();
    float4 av = *(const float4*)&Ar[(size_t)(rb+lr)*256 + k0 + lq];
    float4 bv = *(const float4*)&B [(size_t)(cb+lr)*256 + k0 + lq];
    la[lq+0][lr]=av.x; la[lq+1][lr]=av.y; la[lq+2][lr]=av.z; la[lq+3][lr]=av.w;
    lb[lq+0][lr]=bv.x; lb[lq+1][lr]=bv.y; lb[lq+2][lr]=bv.z; lb[lq+3][lr]=bv.w;
    __syncthreads();
    #pragma unroll
    for (int k = 0; k < 16; k++){
      float4 a = *(const float4*)&la[k][ty*4];
      float4 b = *(const float4*)&lb[k][tx*4];
      float avv[4] = {a.x,a.y,a.z,a.w}, bvv[4] = {b.x,b.y,b.z,b.w};
      #pragma unroll
      for (int u = 0; u < 4; u++)
        #pragma unroll
        for (int v = 0; v < 4; v++) acc[u][v] += avv[u]*bvv[v];
    }
  }
  #pragma unroll
  for (int u = 0; u < 4; u++){
    float4 o = make_float4(acc[u][0], acc[u][1], acc[u][2], acc[u][3]);
    *(float4*)&G[(size_t)(rb+ty*4+u)*NN + cb + tx*4] = o;
  }
}

// ---------------- top-K per row (wave per row), stable tie-break by index ----------------
__global__ __launch_bounds__(256)
void k_topk(const float* __restrict__ G, const float* __restrict__ sq,
            int r0, int* __restrict__ idxo){
  int wid = threadIdx.x >> 6, lane = threadIdx.x & 63;
  int rl = blockIdx.x*4 + wid;
  int gr = r0 + rl;
  const float* row = G + (size_t)rl*NN;
  float sqr = sq[gr];
  float kd[KNN]; int ki[KNN];
  #pragma unroll
  for (int u = 0; u < KNN; u++){ kd[u] = INFINITY; ki[u] = 0x7fffffff; }
  for (int j = lane; j < NN; j += 64){
    float key = sqr + sq[j] - 2.f*row[j];
    float lv = kd[KNN-1]; int li = ki[KNN-1];
    if (key < lv || (key == lv && j < li)){
      float nk = key; int ni = j;
      #pragma unroll
      for (int u = 0; u < KNN; u++){
        bool sw = (nk < kd[u]) || (nk == kd[u] && ni < ki[u]);
        float tv = kd[u]; int ti = ki[u];
        if (sw){ kd[u] = nk; ki[u] = ni; nk = tv; ni = ti; }
      }
    }
  }
  // merge across lanes: 20 rounds of all-reduce min on (val, idx)
  for (int r = 0; r < KNN; r++){
    float cv = kd[0]; int ci = ki[0]; int cl = lane;
    for (int m = 32; m; m >>= 1){
      float ov = __shfl_xor(cv, m); int oi = __shfl_xor(ci, m); int ol = __shfl_xor(cl, m);
      if (ov < cv || (ov == cv && oi < ci)){ cv = ov; ci = oi; cl = ol; }
    }
    if (lane == cl){
      #pragma unroll
      for (int u = 0; u < KNN-1; u++){ kd[u] = kd[u+1]; ki[u] = ki[u+1]; }
      kd[KNN-1] = INFINITY; ki[KNN-1] = 0x7fffffff;
    }
    if (lane == 0) idxo[(size_t)gr*KNN + r] = ci;
  }
}

// ---------------- Wd = Wtop - Wbot ----------------
__global__ void k_wd(const float* __restrict__ W, float* __restrict__ Wd, int rows, int M){
  int t = blockIdx.x*256 + threadIdx.x;
  if (t < rows*M) Wd[t] = W[t] - W[rows*M + t];
}

// ---------------- generic tiled matmul: C = A(nxK) @ B(KxM) [+bias][relu] ----------------
__global__ __launch_bounds__(256)
void k_mm(const float* __restrict__ A, const float* __restrict__ B,
          const float* __restrict__ bias, float* __restrict__ Cout,
          int n, int Kd, int M, int relu){
  __shared__ float la[16][68], lb[16][68];
  int tid = threadIdx.x;
  int rb = blockIdx.y*64, cb = blockIdx.x*64;
  int lr = tid >> 2, lq = (tid & 3)*4;
  int ty = tid >> 4, tx = tid & 15;
  float acc[4][4] = {};
  for (int k0 = 0; k0 < Kd; k0 += 16){
    __syncthreads();
    #pragma unroll
    for (int u = 0; u < 4; u++){
      int k = k0 + lq + u;
      la[lq+u][lr] = (k < Kd) ? A[(size_t)(rb+lr)*Kd + k] : 0.f;
    }
    int kk = tid >> 4; int cc = (tid & 15)*4;
    #pragma unroll
    for (int u = 0; u < 4; u++){
      int c = cb + cc + u; int k = k0 + kk;
      lb[kk][cc+u] = (k < Kd && c < M) ? B[(size_t)k*M + c] : 0.f;
    }
    __syncthreads();
    #pragma unroll
    for (int k = 0; k < 16; k++){
      float4 a = *(const float4*)&la[k][ty*4];
      float4 b = *(const float4*)&lb[k][tx*4];
      float avv[4] = {a.x,a.y,a.z,a.w}, bvv[4] = {b.x,b.y,b.z,b.w};
      #pragma unroll
      for (int u = 0; u < 4; u++)
        #pragma unroll
        for (int v = 0; v < 4; v++) acc[u][v] += avv[u]*bvv[v];
    }
  }
  #pragma unroll
  for (int u = 0; u < 4; u++){
    int r = rb + ty*4 + u;
    #pragma unroll
    for (int v = 0; v < 4; v++){
      int c = cb + tx*4 + v;
      if (c < M){
        float x = acc[u][v] + (bias ? bias[c] : 0.f);
        if (relu) x = fmaxf(x, 0.f);
        Cout[(size_t)r*M + c] = x;
      }
    }
  }
}

// ---------------- stats over A[i]+P[j] per channel ----------------
template<int C>
__global__ __launch_bounds__(256)
void k_stats1(const float* __restrict__ A, const float* __restrict__ P,
              const int* __restrict__ idx, float* __restrict__ ssum, float* __restrict__ ssq){
  __shared__ int si[128], sj[128];
  int tid = threadIdx.x;
  int s0 = blockIdx.x*128;
  if (tid < 128){ si[tid] = (s0 + tid)/KNN; sj[tid] = idx[s0 + tid]; }
  __syncthreads();
  constexpr int MPAR = 256/C;
  int tc = tid % C, sr = tid / C;
  float s = 0.f, q = 0.f;
  for (int m = sr; m < 128; m += MPAR){
    float v = A[(size_t)si[m]*C + tc] + P[(size_t)sj[m]*C + tc];
    s += v; q += v*v;
  }
  if constexpr (MPAR > 1){
    __shared__ float rs[256], rq[256];
    rs[tid] = s; rq[tid] = q; __syncthreads();
    if (sr == 0){
      for (int u = 1; u < MPAR; u++){ s += rs[u*C + tc]; q += rq[u*C + tc]; }
    }
  }
  if (sr == 0){ atomicAdd(&ssum[tc], s); atomicAdd(&ssq[tc], q); }
}

// ---------------- column stats over dense X (rows = N*KNN) ----------------
template<int C>
__global__ __launch_bounds__(256)
void k_colstats(const float* __restrict__ X, float* __restrict__ ssum, float* __restrict__ ssq){
  constexpr int MPAR = 256/C;
  int tid = threadIdx.x;
  int tc = tid % C, sr = tid / C;
  int base = blockIdx.x*256;
  float s = 0.f, q = 0.f;
  for (int m = sr; m < 256; m += MPAR){
    float v = X[(size_t)(base + m)*C + tc];
    s += v; q += v*v;
  }
  if constexpr (MPAR > 1){
    __shared__ float rs[256], rq[256];
    rs[tid] = s; rq[tid] = q; __syncthreads();
    if (sr == 0){
      for (int u = 1; u < MPAR; u++){ s += rs[u*C + tc]; q += rq[u*C + tc]; }
    }
  }
  if (sr == 0){ atomicAdd(&ssum[tc], s); atomicAdd(&ssq[tc], q); }
}

__global__ void k_bn_final(const float* __restrict__ ssum, const float* __restrict__ ssq,
                           const float* __restrict__ g, const float* __restrict__ be,
                           float* __restrict__ sb, float* __restrict__ tb, int C, float invn){
  int c = threadIdx.x;
  if (c < C){
    float mu = ssum[c]*invn;
    float var = fmaxf(ssq[c]*invn - mu*mu, 0.f);
    float s = g[c]*rsqrtf(var + 1e-5f);
    sb[c] = s; tb[c] = be[c] - mu*s;
  }
}

// ---------------- per-edge matmul: out = relu(bn1(A[i]+P[j])) @ W + bias ----------------
template<int C>
__global__ __launch_bounds__(256)
void k_edge_mm(const float* __restrict__ A, const float* __restrict__ P,
               const int* __restrict__ idx, const float* __restrict__ sb,
               const float* __restrict__ tb, const float* __restrict__ W,
               const float* __restrict__ bias, float* __restrict__ out){
  constexpr int BM   = (C == 256) ? 32 : 64;
  constexpr int KT   = (C == 256) ? 16 : 64;
  constexpr int COLG = C/8;
  constexpr int ROWG = 256/COLG;
  constexpr int EPT  = BM/ROWG;
  constexpr int MPAR = 256/C;
  __shared__ float e2[BM][C+1];
  __shared__ float wt[KT][C];
  __shared__ int sj[BM];
  int tid = threadIdx.x;
  int s0 = blockIdx.x*BM;
  if (tid < BM) sj[tid] = idx[s0 + tid];
  __syncthreads();
  for (int mb = 0; mb < BM; mb += MPAR){
    int m = mb + tid / C;
    int c = tid % C;
    int i = (s0 + m)/KNN;
    int j = sj[m];
    float v = (A[(size_t)i*C + c] + P[(size_t)j*C + c])*sb[c] + tb[c];
    e2[m][c] = fmaxf(v, 0.f);
  }
  float acc[EPT][8];
  #pragma unroll
  for (int m = 0; m < EPT; m++)
    #pragma unroll
    for (int u = 0; u < 8; u++) acc[m][u] = 0.f;
  int tr = tid / COLG, tc = tid % COLG;
  for (int kt = 0; kt < C; kt += KT){
    __syncthreads();
    for (int t = tid; t < KT*C; t += 256){
      wt[t / C][t % C] = W[(size_t)(kt + t/C)*C + (t % C)];
    }
    __syncthreads();
    #pragma unroll 4
    for (int k = 0; k < KT; k++){
      float4 w0 = *(const float4*)&wt[k][tc*8];
      float4 w1 = *(const float4*)&wt[k][tc*8 + 4];
      float b[8] = {w0.x,w0.y,w0.z,w0.w,w1.x,w1.y,w1.z,w1.w};
      #pragma unroll
      for (int m = 0; m < EPT; m++){
        float a = e2[tr*EPT + m][kt + k];
        #pragma unroll
        for (int u = 0; u < 8; u++) acc[m][u] += a*b[u];
      }
    }
  }
  #pragma unroll
  for (int m = 0; m < EPT; m++){
    int row = s0 + tr*EPT + m;
    float4 o0, o1;
    o0.x = acc[m][0] + bias[tc*8+0]; o0.y = acc[m][1] + bias[tc*8+1];
    o0.z = acc[m][2] + bias[tc*8+2]; o0.w = acc[m][3] + bias[tc*8+3];
    o1.x = acc[m][4] + bias[tc*8+4]; o1.y = acc[m][5] + bias[tc*8+5];
    o1.z = acc[m][6] + bias[tc*8+6]; o1.w = acc[m][7] + bias[tc*8+7];
    *(float4*)&out[(size_t)row*C + tc*8]     = o0;
    *(float4*)&out[(size_t)row*C + tc*8 + 4] = o1;
  }
}

// ---------------- bn2 + relu + max over K ----------------
template<int C>
__global__ void k_maxpool(const float* __restrict__ X, const float* __restrict__ sb,
                          const float* __restrict__ tb, float* __restrict__ H){
  constexpr int NPB = 256/C;
  int node = blockIdx.x*NPB + threadIdx.x / C;
  int c = threadIdx.x % C;
  float s = sb[c], t = tb[c];
  float mx = 0.f;
  for (int k = 0; k < KNN; k++){
    float v = X[(size_t)(node*KNN + k)*C + c]*s + t;
    mx = fmaxf(mx, v);
  }
  H[(size_t)node*C + c] = mx;
}

// ---------------- gconv aggregation: XA[i] = din[i] * sum_in x[s]*dout[s] ----------------
template<int C>
__global__ void k_agg(const float* __restrict__ X, const int* __restrict__ roff,
                      const int* __restrict__ csr, const float* __restrict__ dout,
                      const float* __restrict__ din, float* __restrict__ XA){
  int i = blockIdx.x; int c = threadIdx.x;
  float acc = 0.f;
  int b = roff[i], e = roff[i+1];
  for (int t = b; t < e; t++){
    int s = csr[t];
    acc += X[(size_t)s*C + c]*dout[s];
  }
  XA[(size_t)i*C + c] = acc*din[i];
}

// ================= host =================
extern "C" void kernel_launch(void* const* d_in, const int* in_sizes, int n_in,
                              void* d_out, int out_size, void* d_ws, size_t ws_size,
                              hipStream_t stream){
  const float* feat = (const float*)d_in[0];
  const int*   src  = (const int*)d_in[1];
  const int*   dst  = (const int*)d_in[2];
  const float* Wc1  = (const float*)d_in[3];
  const float* bc1  = (const float*)d_in[4];
  const float* Wc2  = (const float*)d_in[5];
  const float* bc2  = (const float*)d_in[6];
  const float* Wc3  = (const float*)d_in[7];
  const float* bc3  = (const float*)d_in[8];
  const float* W11  = (const float*)d_in[9];
  const float* b11  = (const float*)d_in[10];
  const float* g11  = (const float*)d_in[11];
  const float* be11 = (const float*)d_in[12];
  const float* W12  = (const float*)d_in[13];
  const float* b12  = (const float*)d_in[14];
  const float* g12  = (const float*)d_in[15];
  const float* be12 = (const float*)d_in[16];
  const float* W21  = (const float*)d_in[17];
  const float* b21  = (const float*)d_in[18];
  const float* g21  = (const float*)d_in[19];
  const float* be21 = (const float*)d_in[20];
  const float* W22  = (const float*)d_in[21];
  const float* b22  = (const float*)d_in[22];
  const float* g22  = (const float*)d_in[23];
  const float* be22 = (const float*)d_in[24];
  float* out = (float*)d_out;

  char* w = (char*)d_ws; size_t off = 0;
  auto alloc = [&](size_t bytes)->void*{
    void* p = w + off;
    off += bytes; off = (off + 255) & ~(size_t)255;
    return p;
  };
  int* cnt_s  = (int*)alloc(NN*4);
  int* cnt_d  = (int*)alloc(NN*4);
  int* roff   = (int*)alloc((NN+1)*4);
  int* cursor = (int*)alloc(NN*4);
  int* csr    = (int*)alloc(NE*4);
  int* idx    = (int*)alloc((size_t)NN*KNN*4);
  float* dout = (float*)alloc(NN*4);
  float* din  = (float*)alloc(NN*4);
  float* sqv  = (float*)alloc(NN*4);
  float* h1   = (float*)alloc((size_t)NN*256*4);
  float* h2   = (float*)alloc((size_t)NN*256*4);
  float* h3   = (float*)alloc((size_t)NN*256*4);
  float* h4   = (float*)alloc((size_t)NN*64*4);
  float* xa   = (float*)alloc((size_t)NN*256*4);
  float* Abuf = (float*)alloc((size_t)NN*256*4);
  float* Pbuf = (float*)alloc((size_t)NN*256*4);
  float* Wd   = (float*)alloc(256*256*4);
  float* ssum = (float*)alloc(256*4);
  float* ssq  = (float*)alloc(256*4);
  float* sbn  = (float*)alloc(256*4);
  float* tbn  = (float*)alloc(256*4);
  float* gram = (float*)alloc((size_t)CH*NN*4);
  float* out2 = (float*)alloc((size_t)NN*KNN*256*4);
  (void)ws_size; (void)n_in; (void)in_sizes; (void)out_size;

  const float invn = 1.0f / (float)(NN*KNN);

  // graph prep
  k_zero_i<<<32, 256, 0, stream>>>(cnt_s, NN);
  k_zero_i<<<32, 256, 0, stream>>>(cnt_d, NN);
  k_zero_i<<<32, 256, 0, stream>>>(cursor, NN);
  k_count<<<NE/256, 256, 0, stream>>>(src, dst, cnt_s, cnt_d);
  k_deg<<<32, 256, 0, stream>>>(cnt_s, cnt_d, dout, din);
  k_scan<<<1, 256, 0, stream>>>(cnt_d, roff);
  k_fill<<<NE/256, 256, 0, stream>>>(src, dst, roff, cursor, csr);

  // gconv1 -> h1
  k_gconv1<<<NN/4, 256, 0, stream>>>(feat, roff, csr, dout, din, Wc1, bc1, h1);

  // ---- edge conv 1 (input h1, 256 -> 256 -> 256) ----
  k_sq<<<NN/4, 256, 0, stream>>>(h1, sqv);
  for (int r0 = 0; r0 < NN; r0 += CH){
    k_gramNT<<<dim3(NN/64, CH/64), 256, 0, stream>>>(h1 + (size_t)r0*256, h1, gram);
    k_topk<<<CH/4, 256, 0, stream>>>(gram, sqv, r0, idx);
  }
  k_wd<<<256, 256, 0, stream>>>(W11, Wd, 256, 256);
  k_mm<<<dim3(4, NN/64), 256, 0, stream>>>(h1, Wd, b11, Abuf, NN, 256, 256, 0);
  k_mm<<<dim3(4, NN/64), 256, 0, stream>>>(h1, W11 + 256*256, nullptr, Pbuf, NN, 256, 256, 0);
  k_zero<<<2, 256, 0, stream>>>(ssum, 256); k_zero<<<2, 256, 0, stream>>>(ssq, 256);
  k_stats1<256><<<NN*KNN/128, 256, 0, stream>>>(Abuf, Pbuf, idx, ssum, ssq);
  k_bn_final<<<1, 256, 0, stream>>>(ssum, ssq, g11, be11, sbn, tbn, 256, invn);
  k_edge_mm<256><<<NN*KNN/32, 256, 0, stream>>>(Abuf, Pbuf, idx, sbn, tbn, W12, b12, out2);
  k_zero<<<2, 256, 0, stream>>>(ssum, 256); k_zero<<<2, 256, 0, stream>>>(ssq, 256);
  k_colstats<256><<<NN*KNN/256, 256, 0, stream>>>(out2, ssum, ssq);
  k_bn_final<<<1, 256, 0, stream>>>(ssum, ssq, g12, be12, sbn, tbn, 256, invn);
  k_maxpool<256><<<NN, 256, 0, stream>>>(out2, sbn, tbn, h2);

  // gconv2 -> h3
  k_agg<256><<<NN, 256, 0, stream>>>(h2, roff, csr, dout, din, xa);
  k_mm<<<dim3(4, NN/64), 256, 0, stream>>>(xa, Wc2, bc2, h3, NN, 256, 256, 1);

  // ---- edge conv 2 (input h3, 256 -> 64 -> 64) ----
  k_sq<<<NN/4, 256, 0, stream>>>(h3, sqv);
  for (int r0 = 0; r0 < NN; r0 += CH){
    k_gramNT<<<dim3(NN/64, CH/64), 256, 0, stream>>>(h3 + (size_t)r0*256, h3, gram);
    k_topk<<<CH/4, 256, 0, stream>>>(gram, sqv, r0, idx);
  }
  k_wd<<<64, 256, 0, stream>>>(W21, Wd, 256, 64);
  k_mm<<<dim3(1, NN/64), 256, 0, stream>>>(h3, Wd, b21, Abuf, NN, 256, 64, 0);
  k_mm<<<dim3(1, NN/64), 256, 0, stream>>>(h3, W21 + 256*64, nullptr, Pbuf, NN, 256, 64, 0);
  k_zero<<<2, 256, 0, stream>>>(ssum, 256); k_zero<<<2, 256, 0, stream>>>(ssq, 256);
  k_stats1<64><<<NN*KNN/128, 256, 0, stream>>>(Abuf, Pbuf, idx, ssum, ssq);
  k_bn_final<<<1, 256, 0, stream>>>(ssum, ssq, g21, be21, sbn, tbn, 64, invn);
  k_edge_mm<64><<<NN*KNN/64, 256, 0, stream>>>(Abuf, Pbuf, idx, sbn, tbn, W22, b22, out2);
  k_zero<<<2, 256, 0, stream>>>(ssum, 256); k_zero<<<2, 256, 0, stream>>>(ssq, 256);
  k_colstats<64><<<NN*KNN/256, 256, 0, stream>>>(out2, ssum, ssq);
  k_bn_final<<<1, 256, 0, stream>>>(ssum, ssq, g22, be22, sbn, tbn, 64, invn);
  k_maxpool<64><<<NN/4, 256, 0, stream>>>(out2, sbn, tbn, h4);

  // gconv3 -> out
  k_agg<64><<<NN, 64, 0, stream>>>(h4, roff, csr, dout, din, xa);
  k_mm<<<dim3(1, NN/64), 256, 0, stream>>>(xa, Wc3, bc3, out, NN, 64, 32, 0);
}

// Round 2
// 3600.152 us; speedup vs baseline: 3.4064x; 3.4064x over previous
//
#include <hip/hip_runtime.h>

#define NN 8192
#define NE 131072
#define KNN 20
#define CH 4096   // gram chunk rows
#define GBM 128
#define GBN 128
#define GBK 64

typedef __attribute__((ext_vector_type(4))) float f32x4;
typedef __attribute__((ext_vector_type(8))) __bf16 bf16x8;

// ---------------- utility ----------------
__global__ void k_zero(float* p, int n){
  int i = blockIdx.x*256 + threadIdx.x;
  if (i < n) p[i] = 0.f;
}
__global__ void k_zero_i(int* p, int n){
  int i = blockIdx.x*256 + threadIdx.x;
  if (i < n) p[i] = 0;
}

__device__ __forceinline__ unsigned short f2bf(float x){
  unsigned u = __float_as_uint(x);
  unsigned r = (u + 0x7fff + ((u >> 16) & 1)) >> 16;
  return (unsigned short)r;
}
__device__ __forceinline__ float bf2f(unsigned short h){
  return __uint_as_float((unsigned)h << 16);
}
__device__ __forceinline__ void gload16(const void* g, void* l){
  __builtin_amdgcn_global_load_lds(
      (const __attribute__((address_space(1))) void*)g,
      (__attribute__((address_space(3))) void*)l, 16, 0, 0);
}

// ---------------- graph prep ----------------
__global__ void k_count(const int* __restrict__ src, const int* __restrict__ dst,
                        int* cs, int* cd){
  int e = blockIdx.x*256 + threadIdx.x;
  if (e < NE){ atomicAdd(&cs[src[e]], 1); atomicAdd(&cd[dst[e]], 1); }
}
__global__ void k_deg(const int* cs, const int* cd, float* dout, float* din){
  int i = blockIdx.x*256 + threadIdx.x;
  if (i < NN){
    dout[i] = rsqrtf((float)max(cs[i], 1));
    din[i]  = rsqrtf((float)max(cd[i], 1));
  }
}
__global__ void k_scan(const int* __restrict__ cnt, int* __restrict__ off){
  __shared__ int sh[256];
  __shared__ int carry;
  int tid = threadIdx.x;
  if (tid == 0) carry = 0;
  __syncthreads();
  for (int base = 0; base < NN; base += 256){
    int v = cnt[base + tid];
    int x = v;
    sh[tid] = x; __syncthreads();
    for (int o = 1; o < 256; o <<= 1){
      int y = (tid >= o) ? sh[tid - o] : 0;
      __syncthreads();
      x += y; sh[tid] = x;
      __syncthreads();
    }
    off[base + tid] = carry + x - v;
    __syncthreads();
    if (tid == 255){
      carry += x;
      if (base + 256 == NN) off[NN] = carry;
    }
    __syncthreads();
  }
}
__global__ void k_fill(const int* __restrict__ src, const int* __restrict__ dst,
                       const int* __restrict__ roff, int* cursor, int* csr){
  int e = blockIdx.x*256 + threadIdx.x;
  if (e < NE){
    int d = dst[e];
    int p = atomicAdd(&cursor[d], 1);
    csr[roff[d] + p] = src[e];
  }
}

// ---------------- gconv1 fused (3 -> 256) ----------------
__global__ void k_gconv1(const float* __restrict__ feat, const int* __restrict__ roff,
                         const int* __restrict__ csr, const float* __restrict__ dout,
                         const float* __restrict__ din, const float* __restrict__ Wc1,
                         const float* __restrict__ bc1, float* __restrict__ h1){
  int wid = threadIdx.x >> 6, lane = threadIdx.x & 63;
  int i = blockIdx.x*4 + wid;
  float a0=0.f, a1=0.f, a2=0.f;
  int beg = roff[i], end = roff[i+1];
  for (int t = beg + lane; t < end; t += 64){
    int s = csr[t]; float w = dout[s];
    a0 += feat[s*3+0]*w; a1 += feat[s*3+1]*w; a2 += feat[s*3+2]*w;
  }
  for (int m = 32; m; m >>= 1){
    a0 += __shfl_xor(a0, m); a1 += __shfl_xor(a1, m); a2 += __shfl_xor(a2, m);
  }
  float dn = din[i];
  a0 *= dn; a1 *= dn; a2 *= dn;
  for (int c = lane; c < 256; c += 64){
    float r = a0*Wc1[c] + a1*Wc1[256+c] + a2*Wc1[512+c] + bc1[c];
    h1[(size_t)i*256 + c] = fmaxf(r, 0.f);
  }
}

// ---------------- row squared norms (C=256) ----------------
__global__ void k_sq(const float* __restrict__ X, float* __restrict__ sq){
  int wid = threadIdx.x >> 6, lane = threadIdx.x & 63;
  int i = blockIdx.x*4 + wid;
  float4 v = *(const float4*)&X[(size_t)i*256 + lane*4];
  float s = v.x*v.x + v.y*v.y + v.z*v.z + v.w*v.w;
  for (int m = 32; m; m >>= 1) s += __shfl_xor(s, m);
  if (lane == 0) sq[i] = s;
}

// ---------------- split f32 -> [hi|lo] bf16, Xcat[n][512] ----------------
__global__ void k_split(const float* __restrict__ X, unsigned short* __restrict__ xcat){
  int row = blockIdx.x, c = threadIdx.x;
  float x = X[(size_t)row*256 + c];
  unsigned short h = f2bf(x);
  unsigned short lo = f2bf(x - bf2f(h));
  xcat[(size_t)row*512 + c] = h;
  xcat[(size_t)row*512 + 256 + c] = lo;
}

// ---------------- MFMA gram: G[chunk row][j] = x_i . x_j (split bf16, K=768) ----------------
// A sections: {hi, lo, hi}; B sections: {hi, hi, lo}
__global__ __launch_bounds__(256)
void k_gram_mfma(const unsigned short* __restrict__ Xcat,
                 float* __restrict__ G, int r0){
  __shared__ unsigned short sA[GBM*GBK];  // 16 KB, swizzled granules
  __shared__ unsigned short sB[GBN*GBK];
  int tid = threadIdx.x;
  int lw = tid >> 6, l = tid & 63;
  int rbl = blockIdx.y*GBM;      // local chunk row base
  int rb = r0 + rbl;             // global source row base (A)
  int cb = blockIdx.x*GBN;       // global source row base (B) = G column base

  // staging source constants: per gload instr a wave writes 1KB = 8 rows x 8 granules
  int srow = l >> 3;             // 0..7
  int scol = (l & 7) ^ srow;     // swizzled source granule (row&7 == srow)
  const unsigned short* srcA[4];
  const unsigned short* srcB[4];
  char* dstA[4]; char* dstB[4];
  #pragma unroll
  for (int i = 0; i < 4; i++){
    int c = lw*4 + i;
    int row = c*8 + srow;
    srcA[i] = Xcat + (size_t)(rb + row)*512 + scol*8;
    srcB[i] = Xcat + (size_t)(cb + row)*512 + scol*8;
    dstA[i] = (char*)sA + c*1024;
    dstB[i] = (char*)sB + c*1024;
  }

  // fragment read offsets (bytes), swizzled: q = col16 ^ (row&7)
  int wm = lw >> 1, wn = lw & 1;
  int fm = l & 15, kg = l >> 4;
  unsigned offA[4][2], offB[4][2];
  #pragma unroll
  for (int mf = 0; mf < 4; mf++){
    int rowa = wm*64 + mf*16 + fm;
    int rowb = wn*64 + mf*16 + fm;
    #pragma unroll
    for (int ks = 0; ks < 2; ks++){
      offA[mf][ks] = rowa*128 + (((unsigned)(ks*4 + kg) ^ (rowa & 7)))*16;
      offB[mf][ks] = rowb*128 + (((unsigned)(ks*4 + kg) ^ (rowb & 7)))*16;
    }
  }

  f32x4 acc[4][4];
  #pragma unroll
  for (int m = 0; m < 4; m++)
    #pragma unroll
    for (int n = 0; n < 4; n++) acc[m][n] = (f32x4){0.f,0.f,0.f,0.f};

  #pragma unroll
  for (int s = 0; s < 12; s++){
    int sec = s >> 2;
    int inner = (s & 3)*64;
    int cbA = (sec == 1 ? 256 : 0) + inner;
    int cbB = (sec == 2 ? 256 : 0) + inner;
    #pragma unroll
    for (int i = 0; i < 4; i++){
      gload16(srcA[i] + cbA, dstA[i]);
      gload16(srcB[i] + cbB, dstB[i]);
    }
    __syncthreads();   // drains vmcnt before any wave reads LDS
    #pragma unroll
    for (int ks = 0; ks < 2; ks++){
      bf16x8 a[4], b[4];
      #pragma unroll
      for (int mf = 0; mf < 4; mf++) a[mf] = *(const bf16x8*)((const char*)sA + offA[mf][ks]);
      #pragma unroll
      for (int nf = 0; nf < 4; nf++) b[nf] = *(const bf16x8*)((const char*)sB + offB[nf][ks]);
      #pragma unroll
      for (int mf = 0; mf < 4; mf++)
        #pragma unroll
        for (int nf = 0; nf < 4; nf++)
          acc[mf][nf] = __builtin_amdgcn_mfma_f32_16x16x32_bf16(a[mf], b[nf], acc[mf][nf], 0, 0, 0);
    }
    __syncthreads();   // protect LDS before next stage overwrites
  }

  // C/D layout: col = lane&15, row = (lane>>4)*4 + reg
  #pragma unroll
  for (int mf = 0; mf < 4; mf++){
    int orow = rbl + wm*64 + mf*16 + kg*4;
    #pragma unroll
    for (int nf = 0; nf < 4; nf++){
      int ocol = cb + wn*64 + nf*16 + fm;
      #pragma unroll
      for (int r = 0; r < 4; r++)
        G[(size_t)(orow + r)*NN + ocol] = acc[mf][nf][r];
    }
  }
}

// ---------------- top-K per row (wave per row), stable tie-break by index ----------------
__global__ __launch_bounds__(256)
void k_topk(const float* __restrict__ G, const float* __restrict__ sq,
            int r0, int* __restrict__ idxo){
  int wid = threadIdx.x >> 6, lane = threadIdx.x & 63;
  int rl = blockIdx.x*4 + wid;
  int gr = r0 + rl;
  const float* row = G + (size_t)rl*NN;
  float sqr = sq[gr];
  float kd[KNN]; int ki[KNN];
  #pragma unroll
  for (int u = 0; u < KNN; u++){ kd[u] = INFINITY; ki[u] = 0x7fffffff; }
  for (int j = lane; j < NN; j += 64){
    float key = sqr + sq[j] - 2.f*row[j];
    float lv = kd[KNN-1]; int li = ki[KNN-1];
    if (key < lv || (key == lv && j < li)){
      float nk = key; int ni = j;
      #pragma unroll
      for (int u = 0; u < KNN; u++){
        bool sw = (nk < kd[u]) || (nk == kd[u] && ni < ki[u]);
        float tv = kd[u]; int ti = ki[u];
        if (sw){ kd[u] = nk; ki[u] = ni; nk = tv; ni = ti; }
      }
    }
  }
  for (int r = 0; r < KNN; r++){
    float cv = kd[0]; int ci = ki[0]; int cl = lane;
    for (int m = 32; m; m >>= 1){
      float ov = __shfl_xor(cv, m); int oi = __shfl_xor(ci, m); int ol = __shfl_xor(cl, m);
      if (ov < cv || (ov == cv && oi < ci)){ cv = ov; ci = oi; cl = ol; }
    }
    if (lane == cl){
      #pragma unroll
      for (int u = 0; u < KNN-1; u++){ kd[u] = kd[u+1]; ki[u] = ki[u+1]; }
      kd[KNN-1] = INFINITY; ki[KNN-1] = 0x7fffffff;
    }
    if (lane == 0) idxo[(size_t)gr*KNN + r] = ci;
  }
}

// ---------------- Wd = Wtop - Wbot ----------------
__global__ void k_wd(const float* __restrict__ W, float* __restrict__ Wd, int rows, int M){
  int t = blockIdx.x*256 + threadIdx.x;
  if (t < rows*M) Wd[t] = W[t] - W[rows*M + t];
}

// ---------------- generic tiled matmul: C = A(nxK) @ B(KxM) [+bias][relu] ----------------
__global__ __launch_bounds__(256)
void k_mm(const float* __restrict__ A, const float* __restrict__ B,
          const float* __restrict__ bias, float* __restrict__ Cout,
          int n, int Kd, int M, int relu){
  __shared__ float la[16][68], lb[16][68];
  int tid = threadIdx.x;
  int rb = blockIdx.y*64, cb = blockIdx.x*64;
  int lr = tid >> 2, lq = (tid & 3)*4;
  int ty = tid >> 4, tx = tid & 15;
  float acc[4][4] = {};
  for (int k0 = 0; k0 < Kd; k0 += 16){
    __syncthreads();
    #pragma unroll
    for (int u = 0; u < 4; u++){
      int k = k0 + lq + u;
      la[lq+u][lr] = (k < Kd) ? A[(size_t)(rb+lr)*Kd + k] : 0.f;
    }
    int kk = tid >> 4; int cc = (tid & 15)*4;
    #pragma unroll
    for (int u = 0; u < 4; u++){
      int c = cb + cc + u; int k = k0 + kk;
      lb[kk][cc+u] = (k < Kd && c < M) ? B[(size_t)k*M + c] : 0.f;
    }
    __syncthreads();
    #pragma unroll
    for (int k = 0; k < 16; k++){
      float4 a = *(const float4*)&la[k][ty*4];
      float4 b = *(const float4*)&lb[k][tx*4];
      float avv[4] = {a.x,a.y,a.z,a.w}, bvv[4] = {b.x,b.y,b.z,b.w};
      #pragma unroll
      for (int u = 0; u < 4; u++)
        #pragma unroll
        for (int v = 0; v < 4; v++) acc[u][v] += avv[u]*bvv[v];
    }
  }
  #pragma unroll
  for (int u = 0; u < 4; u++){
    int r = rb + ty*4 + u;
    #pragma unroll
    for (int v = 0; v < 4; v++){
      int c = cb + tx*4 + v;
      if (c < M){
        float x = acc[u][v] + (bias ? bias[c] : 0.f);
        if (relu) x = fmaxf(x, 0.f);
        Cout[(size_t)r*M + c] = x;
      }
    }
  }
}

// ---------------- stats over A[i]+P[j] per channel ----------------
template<int C>
__global__ __launch_bounds__(256)
void k_stats1(const float* __restrict__ A, const float* __restrict__ P,
              const int* __restrict__ idx, float* __restrict__ ssum, float* __restrict__ ssq){
  __shared__ int si[128], sj[128];
  int tid = threadIdx.x;
  int s0 = blockIdx.x*128;
  if (tid < 128){ si[tid] = (s0 + tid)/KNN; sj[tid] = idx[s0 + tid]; }
  __syncthreads();
  constexpr int MPAR = 256/C;
  int tc = tid % C, sr = tid / C;
  float s = 0.f, q = 0.f;
  for (int m = sr; m < 128; m += MPAR){
    float v = A[(size_t)si[m]*C + tc] + P[(size_t)sj[m]*C + tc];
    s += v; q += v*v;
  }
  if constexpr (MPAR > 1){
    __shared__ float rs[256], rq[256];
    rs[tid] = s; rq[tid] = q; __syncthreads();
    if (sr == 0){
      for (int u = 1; u < MPAR; u++){ s += rs[u*C + tc]; q += rq[u*C + tc]; }
    }
  }
  if (sr == 0){ atomicAdd(&ssum[tc], s); atomicAdd(&ssq[tc], q); }
}

// ---------------- column stats over dense X (rows = N*KNN) ----------------
template<int C>
__global__ __launch_bounds__(256)
void k_colstats(const float* __restrict__ X, float* __restrict__ ssum, float* __restrict__ ssq){
  constexpr int MPAR = 256/C;
  int tid = threadIdx.x;
  int tc = tid % C, sr = tid / C;
  int base = blockIdx.x*256;
  float s = 0.f, q = 0.f;
  for (int m = sr; m < 256; m += MPAR){
    float v = X[(size_t)(base + m)*C + tc];
    s += v; q += v*v;
  }
  if constexpr (MPAR > 1){
    __shared__ float rs[256], rq[256];
    rs[tid] = s; rq[tid] = q; __syncthreads();
    if (sr == 0){
      for (int u = 1; u < MPAR; u++){ s += rs[u*C + tc]; q += rq[u*C + tc]; }
    }
  }
  if (sr == 0){ atomicAdd(&ssum[tc], s); atomicAdd(&ssq[tc], q); }
}

__global__ void k_bn_final(const float* __restrict__ ssum, const float* __restrict__ ssq,
                           const float* __restrict__ g, const float* __restrict__ be,
                           float* __restrict__ sb, float* __restrict__ tb, int C, float invn){
  int c = threadIdx.x;
  if (c < C){
    float mu = ssum[c]*invn;
    float var = fmaxf(ssq[c]*invn - mu*mu, 0.f);
    float s = g[c]*rsqrtf(var + 1e-5f);
    sb[c] = s; tb[c] = be[c] - mu*s;
  }
}

// ---------------- per-edge matmul: out = relu(bn1(A[i]+P[j])) @ W + bias ----------------
template<int C>
__global__ __launch_bounds__(256)
void k_edge_mm(const float* __restrict__ A, const float* __restrict__ P,
               const int* __restrict__ idx, const float* __restrict__ sb,
               const float* __restrict__ tb, const float* __restrict__ W,
               const float* __restrict__ bias, float* __restrict__ out){
  constexpr int BM   = (C == 256) ? 32 : 64;
  constexpr int KT   = (C == 256) ? 16 : 64;
  constexpr int COLG = C/8;
  constexpr int ROWG = 256/COLG;
  constexpr int EPT  = BM/ROWG;
  constexpr int MPAR = 256/C;
  __shared__ float e2[BM][C+1];
  __shared__ float wt[KT][C+4];
  __shared__ int sj[BM];
  int tid = threadIdx.x;
  int s0 = blockIdx.x*BM;
  if (tid < BM) sj[tid] = idx[s0 + tid];
  __syncthreads();
  for (int mb = 0; mb < BM; mb += MPAR){
    int m = mb + tid / C;
    int c = tid % C;
    int i = (s0 + m)/KNN;
    int j = sj[m];
    float v = (A[(size_t)i*C + c] + P[(size_t)j*C + c])*sb[c] + tb[c];
    e2[m][c] = fmaxf(v, 0.f);
  }
  float acc[EPT][8];
  #pragma unroll
  for (int m = 0; m < EPT; m++)
    #pragma unroll
    for (int u = 0; u < 8; u++) acc[m][u] = 0.f;
  int tr = tid / COLG, tc = tid % COLG;
  for (int kt = 0; kt < C; kt += KT){
    __syncthreads();
    for (int t = tid; t < KT*C; t += 256){
      wt[t / C][t % C] = W[(size_t)(kt + t/C)*C + (t % C)];
    }
    __syncthreads();
    #pragma unroll 4
    for (int k = 0; k < KT; k++){
      float4 w0 = *(const float4*)&wt[k][tc*8];
      float4 w1 = *(const float4*)&wt[k][tc*8 + 4];
      float b[8] = {w0.x,w0.y,w0.z,w0.w,w1.x,w1.y,w1.z,w1.w};
      #pragma unroll
      for (int m = 0; m < EPT; m++){
        float a = e2[tr*EPT + m][kt + k];
        #pragma unroll
        for (int u = 0; u < 8; u++) acc[m][u] += a*b[u];
      }
    }
  }
  #pragma unroll
  for (int m = 0; m < EPT; m++){
    int row = s0 + tr*EPT + m;
    float4 o0, o1;
    o0.x = acc[m][0] + bias[tc*8+0]; o0.y = acc[m][1] + bias[tc*8+1];
    o0.z = acc[m][2] + bias[tc*8+2]; o0.w = acc[m][3] + bias[tc*8+3];
    o1.x = acc[m][4] + bias[tc*8+4]; o1.y = acc[m][5] + bias[tc*8+5];
    o1.z = acc[m][6] + bias[tc*8+6]; o1.w = acc[m][7] + bias[tc*8+7];
    *(float4*)&out[(size_t)row*C + tc*8]     = o0;
    *(float4*)&out[(size_t)row*C + tc*8 + 4] = o1;
  }
}

// ---------------- bn2 + relu + max over K ----------------
template<int C>
__global__ void k_maxpool(const float* __restrict__ X, const float* __restrict__ sb,
                          const float* __restrict__ tb, float* __restrict__ H){
  constexpr int NPB = 256/C;
  int node = blockIdx.x*NPB + threadIdx.x / C;
  int c = threadIdx.x % C;
  float s = sb[c], t = tb[c];
  float mx = 0.f;
  for (int k = 0; k < KNN; k++){
    float v = X[(size_t)(node*KNN + k)*C + c]*s + t;
    mx = fmaxf(mx, v);
  }
  H[(size_t)node*C + c] = mx;
}

// ---------------- gconv aggregation ----------------
template<int C>
__global__ void k_agg(const float* __restrict__ X, const int* __restrict__ roff,
                      const int* __restrict__ csr, const float* __restrict__ dout,
                      const float* __restrict__ din, float* __restrict__ XA){
  int i = blockIdx.x; int c = threadIdx.x;
  float acc = 0.f;
  int b = roff[i], e = roff[i+1];
  for (int t = b; t < e; t++){
    int s = csr[t];
    acc += X[(size_t)s*C + c]*dout[s];
  }
  XA[(size_t)i*C + c] = acc*din[i];
}

// ================= host =================
extern "C" void kernel_launch(void* const* d_in, const int* in_sizes, int n_in,
                              void* d_out, int out_size, void* d_ws, size_t ws_size,
                              hipStream_t stream){
  const float* feat = (const float*)d_in[0];
  const int*   src  = (const int*)d_in[1];
  const int*   dst  = (const int*)d_in[2];
  const float* Wc1  = (const float*)d_in[3];
  const float* bc1  = (const float*)d_in[4];
  const float* Wc2  = (const float*)d_in[5];
  const float* bc2  = (const float*)d_in[6];
  const float* Wc3  = (const float*)d_in[7];
  const float* bc3  = (const float*)d_in[8];
  const float* W11  = (const float*)d_in[9];
  const float* b11  = (const float*)d_in[10];
  const float* g11  = (const float*)d_in[11];
  const float* be11 = (const float*)d_in[12];
  const float* W12  = (const float*)d_in[13];
  const float* b12  = (const float*)d_in[14];
  const float* g12  = (const float*)d_in[15];
  const float* be12 = (const float*)d_in[16];
  const float* W21  = (const float*)d_in[17];
  const float* b21  = (const float*)d_in[18];
  const float* g21  = (const float*)d_in[19];
  const float* be21 = (const float*)d_in[20];
  const float* W22  = (const float*)d_in[21];
  const float* b22  = (const float*)d_in[22];
  const float* g22  = (const float*)d_in[23];
  const float* be22 = (const float*)d_in[24];
  float* out = (float*)d_out;

  char* w = (char*)d_ws; size_t off = 0;
  auto alloc = [&](size_t bytes)->void*{
    void* p = w + off;
    off += bytes; off = (off + 255) & ~(size_t)255;
    return p;
  };
  int* cnt_s  = (int*)alloc(NN*4);
  int* cnt_d  = (int*)alloc(NN*4);
  int* roff   = (int*)alloc((NN+1)*4);
  int* cursor = (int*)alloc(NN*4);
  int* csr    = (int*)alloc(NE*4);
  int* idx    = (int*)alloc((size_t)NN*KNN*4);
  float* dout = (float*)alloc(NN*4);
  float* din  = (float*)alloc(NN*4);
  float* sqv  = (float*)alloc(NN*4);
  float* h1   = (float*)alloc((size_t)NN*256*4);
  float* h2   = (float*)alloc((size_t)NN*256*4);
  float* h3   = (float*)alloc((size_t)NN*256*4);
  float* h4   = (float*)alloc((size_t)NN*64*4);
  float* xa   = (float*)alloc((size_t)NN*256*4);
  float* Abuf = (float*)alloc((size_t)NN*256*4);
  float* Pbuf = (float*)alloc((size_t)NN*256*4);
  float* Wd   = (float*)alloc(256*256*4);
  float* ssum = (float*)alloc(256*4);
  float* ssq  = (float*)alloc(256*4);
  float* sbn  = (float*)alloc(256*4);
  float* tbn  = (float*)alloc(256*4);
  float* out2 = (float*)alloc((size_t)NN*KNN*256*4);   // 167.8 MB
  // kNN scratch aliases out2 (consumed before edge_mm writes out2):
  float* gram = out2;                                        // CH*NN*4 = 134.2 MB
  unsigned short* xcat = (unsigned short*)(out2 + (size_t)CH*NN);  // 8.4 MB
  (void)ws_size; (void)n_in; (void)in_sizes; (void)out_size;

  const float invn = 1.0f / (float)(NN*KNN);

  // graph prep
  k_zero_i<<<32, 256, 0, stream>>>(cnt_s, NN);
  k_zero_i<<<32, 256, 0, stream>>>(cnt_d, NN);
  k_zero_i<<<32, 256, 0, stream>>>(cursor, NN);
  k_count<<<NE/256, 256, 0, stream>>>(src, dst, cnt_s, cnt_d);
  k_deg<<<32, 256, 0, stream>>>(cnt_s, cnt_d, dout, din);
  k_scan<<<1, 256, 0, stream>>>(cnt_d, roff);
  k_fill<<<NE/256, 256, 0, stream>>>(src, dst, roff, cursor, csr);

  // gconv1 -> h1
  k_gconv1<<<NN/4, 256, 0, stream>>>(feat, roff, csr, dout, din, Wc1, bc1, h1);

  // ---- edge conv 1 (input h1, 256 -> 256 -> 256) ----
  k_sq<<<NN/4, 256, 0, stream>>>(h1, sqv);
  k_split<<<NN, 256, 0, stream>>>(h1, xcat);
  for (int r0 = 0; r0 < NN; r0 += CH){
    k_gram_mfma<<<dim3(NN/GBN, CH/GBM), 256, 0, stream>>>(xcat, gram, r0);
    k_topk<<<CH/4, 256, 0, stream>>>(gram, sqv, r0, idx);
  }
  k_wd<<<256, 256, 0, stream>>>(W11, Wd, 256, 256);
  k_mm<<<dim3(4, NN/64), 256, 0, stream>>>(h1, Wd, b11, Abuf, NN, 256, 256, 0);
  k_mm<<<dim3(4, NN/64), 256, 0, stream>>>(h1, W11 + 256*256, nullptr, Pbuf, NN, 256, 256, 0);
  k_zero<<<2, 256, 0, stream>>>(ssum, 256); k_zero<<<2, 256, 0, stream>>>(ssq, 256);
  k_stats1<256><<<NN*KNN/128, 256, 0, stream>>>(Abuf, Pbuf, idx, ssum, ssq);
  k_bn_final<<<1, 256, 0, stream>>>(ssum, ssq, g11, be11, sbn, tbn, 256, invn);
  k_edge_mm<256><<<NN*KNN/32, 256, 0, stream>>>(Abuf, Pbuf, idx, sbn, tbn, W12, b12, out2);
  k_zero<<<2, 256, 0, stream>>>(ssum, 256); k_zero<<<2, 256, 0, stream>>>(ssq, 256);
  k_colstats<256><<<NN*KNN/256, 256, 0, stream>>>(out2, ssum, ssq);
  k_bn_final<<<1, 256, 0, stream>>>(ssum, ssq, g12, be12, sbn, tbn, 256, invn);
  k_maxpool<256><<<NN, 256, 0, stream>>>(out2, sbn, tbn, h2);

  // gconv2 -> h3
  k_agg<256><<<NN, 256, 0, stream>>>(h2, roff, csr, dout, din, xa);
  k_mm<<<dim3(4, NN/64), 256, 0, stream>>>(xa, Wc2, bc2, h3, NN, 256, 256, 1);

  // ---- edge conv 2 (input h3, 256 -> 64 -> 64) ----
  k_sq<<<NN/4, 256, 0, stream>>>(h3, sqv);
  k_split<<<NN, 256, 0, stream>>>(h3, xcat);
  for (int r0 = 0; r0 < NN; r0 += CH){
    k_gram_mfma<<<dim3(NN/GBN, CH/GBM), 256, 0, stream>>>(xcat, gram, r0);
    k_topk<<<CH/4, 256, 0, stream>>>(gram, sqv, r0, idx);
  }
  k_wd<<<64, 256, 0, stream>>>(W21, Wd, 256, 64);
  k_mm<<<dim3(1, NN/64), 256, 0, stream>>>(h3, Wd, b21, Abuf, NN, 256, 64, 0);
  k_mm<<<dim3(1, NN/64), 256, 0, stream>>>(h3, W21 + 256*64, nullptr, Pbuf, NN, 256, 64, 0);
  k_zero<<<2, 256, 0, stream>>>(ssum, 256); k_zero<<<2, 256, 0, stream>>>(ssq, 256);
  k_stats1<64><<<NN*KNN/128, 256, 0, stream>>>(Abuf, Pbuf, idx, ssum, ssq);
  k_bn_final<<<1, 256, 0, stream>>>(ssum, ssq, g21, be21, sbn, tbn, 64, invn);
  k_edge_mm<64><<<NN*KNN/64, 256, 0, stream>>>(Abuf, Pbuf, idx, sbn, tbn, W22, b22, out2);
  k_zero<<<2, 256, 0, stream>>>(ssum, 256); k_zero<<<2, 256, 0, stream>>>(ssq, 256);
  k_colstats<64><<<NN*KNN/256, 256, 0, stream>>>(out2, ssum, ssq);
  k_bn_final<<<1, 256, 0, stream>>>(ssum, ssq, g22, be22, sbn, tbn, 64, invn);
  k_maxpool<64><<<NN/4, 256, 0, stream>>>(out2, sbn, tbn, h4);

  // gconv3 -> out
  k_agg<64><<<NN, 64, 0, stream>>>(h4, roff, csr, dout, din, xa);
  k_mm<<<dim3(1, NN/64), 256, 0, stream>>>(xa, Wc3, bc3, out, NN, 64, 32, 0);
}